// Round 3
// baseline (873.949 us; speedup 1.0000x reference)
//
#include <hip/hip_runtime.h>

#define BN_EPS 1e-5f

// ---------------- init / degree / histogram ----------------

__global__ void zero_kernel(int* __restrict__ deg_cnt, int* __restrict__ cnt_b,
                            float* __restrict__ bn, int n, int nb) {
  int stride = gridDim.x * blockDim.x;
  for (int i = blockIdx.x * blockDim.x + threadIdx.x; i < n; i += stride) {
    deg_cnt[i] = 0;
    if (i < nb) cnt_b[i] = 0;
    if (i < 512) bn[i] = 0.f;
  }
}

__global__ void hist_kernel(const int* __restrict__ dst, const int* __restrict__ batch,
                            int* __restrict__ deg_cnt, int* __restrict__ cnt_b,
                            int E, int n) {
  int stride = gridDim.x * blockDim.x;
  for (int i = blockIdx.x * blockDim.x + threadIdx.x; i < E; i += stride) {
    atomicAdd(&deg_cnt[dst[i]], 1);
    if (i < n) atomicAdd(&cnt_b[batch[i]], 1);
  }
}

__global__ void dinv_kernel(const int* __restrict__ deg_cnt, float* __restrict__ dinv, int n) {
  int i = blockIdx.x * blockDim.x + threadIdx.x;
  if (i < n) dinv[i] = rsqrtf((float)deg_cnt[i] + 1.0f);
}

// ---------------- 3-phase exclusive scan for CSR offsets ----------------

__global__ __launch_bounds__(1024) void scan_p1(const int* __restrict__ cnt,
                                                int* __restrict__ offs,
                                                int* __restrict__ bsum, int n) {
  __shared__ int sh[1024];
  int t = threadIdx.x;
  int i = blockIdx.x * 1024 + t;
  int v = (i < n) ? cnt[i] : 0;
  sh[t] = v;
  __syncthreads();
  for (int d = 1; d < 1024; d <<= 1) {
    int x = (t >= d) ? sh[t - d] : 0;
    __syncthreads();
    sh[t] += x;
    __syncthreads();
  }
  if (i < n) offs[i] = sh[t] - v;  // exclusive
  if (t == 1023) bsum[blockIdx.x] = sh[t];
}

__global__ void scan_p2(int* __restrict__ bsum, int nb) {
  __shared__ int sh[128];
  int t = threadIdx.x;
  int v = (t < nb) ? bsum[t] : 0;
  sh[t] = v;
  __syncthreads();
  for (int d = 1; d < 128; d <<= 1) {
    int x = (t >= d) ? sh[t - d] : 0;
    __syncthreads();
    sh[t] += x;
    __syncthreads();
  }
  if (t < nb) bsum[t] = sh[t] - v;
}

__global__ __launch_bounds__(1024) void scan_p3(int* __restrict__ offs, int* __restrict__ cursor,
                                                const int* __restrict__ bsum, int n, int E) {
  int i = blockIdx.x * 1024 + threadIdx.x;
  if (i < n) {
    int o = offs[i] + bsum[blockIdx.x];
    offs[i] = o;
    cursor[i] = o;
  }
  if (i == 0) offs[n] = E;
}

__global__ __launch_bounds__(1024) void scan_batch(const int* __restrict__ cnt_b,
                                                   int* __restrict__ goffs, int B) {
  __shared__ int sh[1024];
  int t = threadIdx.x;
  int v = (t < B) ? cnt_b[t] : 0;
  sh[t] = v;
  __syncthreads();
  for (int d = 1; d < 1024; d <<= 1) {
    int x = (t >= d) ? sh[t - d] : 0;
    __syncthreads();
    sh[t] += x;
    __syncthreads();
  }
  if (t < B) goffs[t] = sh[t] - v;
}

__global__ void csr_fill(const int* __restrict__ dst, const int* __restrict__ src,
                         int* __restrict__ cursor, int* __restrict__ csr, int E) {
  int stride = gridDim.x * blockDim.x;
  for (int e = blockIdx.x * blockDim.x + threadIdx.x; e < E; e += stride) {
    int d = dst[e];
    int pos = atomicAdd(&cursor[d], 1);
    csr[pos] = src[e];
  }
}

// ---------------- GEMM: out[r][f] = dinv[r] * sum_k T(A[r][k]) * W[k][f] ----------------
// T = identity (layer1) or fused BN+ReLU: relu(v*ta[k]+tc[k]) (layers 2,3)

template <int K, int F, bool TRANS>
__global__ __launch_bounds__(256) void gemm_kernel(
    const float* __restrict__ A, const float* __restrict__ W,
    const float* __restrict__ ta, const float* __restrict__ tc,
    const float* __restrict__ dinv, float* __restrict__ out, int n) {
  __shared__ float Ws[K * F];
  __shared__ float As[64 * (K + 1)];
  int tid = threadIdx.x;
  int row0 = blockIdx.x * 64;
  for (int i = tid; i < K * F; i += 256) Ws[i] = W[i];
  for (int i = tid; i < 64 * K; i += 256) {
    int r = i / K, k = i - r * K;
    int gr = row0 + r;
    float v = (gr < n) ? A[(size_t)gr * K + k] : 0.f;
    if constexpr (TRANS) v = fmaxf(v * ta[k] + tc[k], 0.f);
    As[r * (K + 1) + k] = v;
  }
  __syncthreads();
  constexpr int FC = F / 4;
  int rl = tid >> 2, fs = tid & 3;
  float acc[FC];
#pragma unroll
  for (int j = 0; j < FC; j++) acc[j] = 0.f;
  const float* wbase = &Ws[fs * FC];
  const float* abase = &As[rl * (K + 1)];
  for (int k = 0; k < K; k++) {
    float a = abase[k];
#pragma unroll
    for (int j = 0; j < FC; j++) acc[j] += a * wbase[k * F + j];
  }
  int gr = row0 + rl;
  if (gr < n) {
    float s = dinv[gr];
    float4* op = (float4*)&out[(size_t)gr * F + fs * FC];
#pragma unroll
    for (int j = 0; j < FC; j += 4) {
      op[j >> 2] = make_float4(acc[j] * s, acc[j + 1] * s, acc[j + 2] * s, acc[j + 3] * s);
    }
  }
}

// ---------------- Aggregation: out[i] = dinv[i]*(hs[i] + sum_nbr hs[src]) + b ----------------
// F=64 variant also accumulates BN partial sums (per-feature sum / sumsq).

__global__ __launch_bounds__(256) void agg64_kernel(
    const float* __restrict__ hs, const int* __restrict__ offs, const int* __restrict__ csr,
    const float* __restrict__ dinv, const float* __restrict__ bias,
    float* __restrict__ out, float* __restrict__ bn_sum, float* __restrict__ bn_sq, int n) {
  int lane = threadIdx.x & 63;
  int wid = threadIdx.x >> 6;
  int gw = blockIdx.x * 4 + wid;
  int nw = gridDim.x * 4;
  float b = bias[lane];
  float s = 0.f, ss = 0.f;
  for (int i = gw; i < n; i += nw) {
    float acc = hs[(size_t)i * 64 + lane];
    int st = offs[i], en = offs[i + 1];
    for (int base = st; base < en; base += 64) {
      int idx = base + lane;
      int v = (idx < en) ? csr[idx] : 0;
      int cnt = min(64, en - base);
      int j = 0;
      for (; j + 1 < cnt; j += 2) {
        int s0 = __shfl(v, j), s1 = __shfl(v, j + 1);
        acc += hs[(size_t)s0 * 64 + lane] + hs[(size_t)s1 * 64 + lane];
      }
      if (j < cnt) {
        int s0 = __shfl(v, j);
        acc += hs[(size_t)s0 * 64 + lane];
      }
    }
    float o = acc * dinv[i] + b;
    out[(size_t)i * 64 + lane] = o;
    s += o;
    ss += o * o;
  }
  __shared__ float red[2][4][64];
  red[0][wid][lane] = s;
  red[1][wid][lane] = ss;
  __syncthreads();
  if (wid == 0) {
    float t0 = red[0][0][lane] + red[0][1][lane] + red[0][2][lane] + red[0][3][lane];
    float t1 = red[1][0][lane] + red[1][1][lane] + red[1][2][lane] + red[1][3][lane];
    atomicAdd(&bn_sum[lane], t0);
    atomicAdd(&bn_sq[lane], t1);
  }
}

__global__ __launch_bounds__(256) void agg128_kernel(
    const float* __restrict__ hs, const int* __restrict__ offs, const int* __restrict__ csr,
    const float* __restrict__ dinv, const float* __restrict__ bias,
    float* __restrict__ out, int n) {
  int lane = threadIdx.x & 63;
  int wid = threadIdx.x >> 6;
  int gw = blockIdx.x * 4 + wid;
  int nw = gridDim.x * 4;
  const float2* hs2 = (const float2*)hs;
  float2 b2 = ((const float2*)bias)[lane];
  for (int i = gw; i < n; i += nw) {
    float2 acc = hs2[(size_t)i * 64 + lane];
    int st = offs[i], en = offs[i + 1];
    for (int base = st; base < en; base += 64) {
      int idx = base + lane;
      int v = (idx < en) ? csr[idx] : 0;
      int cnt = min(64, en - base);
      int j = 0;
      for (; j + 1 < cnt; j += 2) {
        int s0 = __shfl(v, j), s1 = __shfl(v, j + 1);
        float2 a0 = hs2[(size_t)s0 * 64 + lane], a1 = hs2[(size_t)s1 * 64 + lane];
        acc.x += a0.x + a1.x;
        acc.y += a0.y + a1.y;
      }
      if (j < cnt) {
        int s0 = __shfl(v, j);
        float2 a0 = hs2[(size_t)s0 * 64 + lane];
        acc.x += a0.x;
        acc.y += a0.y;
      }
    }
    float dv = dinv[i];
    float2 o;
    o.x = acc.x * dv + b2.x;
    o.y = acc.y * dv + b2.y;
    ((float2*)out)[(size_t)i * 64 + lane] = o;
  }
}

// ---------------- BN finalize: fold (mu, rstd, gamma, beta) -> affine (a, c) ----------------

__global__ void bn_final_kernel(const float* __restrict__ sum, const float* __restrict__ sq,
                                const float* __restrict__ g, const float* __restrict__ bt,
                                float* __restrict__ a, float* __restrict__ c, float n) {
  int f = threadIdx.x;
  float mu = sum[f] / n;
  float var = fmaxf(sq[f] / n - mu * mu, 0.f);
  float rstd = rsqrtf(var + BN_EPS);
  float av = g[f] * rstd;
  a[f] = av;
  c[f] = bt[f] - mu * av;
}

// ---------------- pool: mean over each graph's (contiguous) node range ----------------

__global__ __launch_bounds__(128) void pool_kernel(const float* __restrict__ agg3,
                                                   const int* __restrict__ goffs,
                                                   const int* __restrict__ cnt_b,
                                                   float* __restrict__ enc, int B) {
  int b = blockIdx.x;
  int f = threadIdx.x;
  int st = goffs[b], c = cnt_b[b];
  float sum = 0.f;
  for (int r = 0; r < c; r++) sum += agg3[(size_t)(st + r) * 128 + f];
  enc[(size_t)b * 128 + f] = sum / (float)max(c, 1);
}

// ---------------- heads: 16 graphs per block, tiny LDS GEMMs ----------------

__global__ __launch_bounds__(256) void heads_kernel(
    const float* __restrict__ enc,
    const float* __restrict__ Wo1, const float* __restrict__ bo1,
    const float* __restrict__ Wo2, const float* __restrict__ bo2,
    const float* __restrict__ Wp1, const float* __restrict__ bp1,
    const float* __restrict__ Wp2, const float* __restrict__ bp2,
    const float* __restrict__ Wp3, const float* __restrict__ bp3,
    const float* __restrict__ Wd1, const float* __restrict__ bd1,
    const float* __restrict__ Wd2, const float* __restrict__ bd2,
    float* __restrict__ out_op, float* __restrict__ out_p, float* __restrict__ out_d, int B) {
  __shared__ float es[16 * 128];
  __shared__ float t1[16 * 64];
  __shared__ float t2[16 * 64];
  int tid = threadIdx.x;
  int g0 = blockIdx.x * 16;
  for (int i = tid; i < 16 * 128; i += 256) es[i] = enc[(size_t)g0 * 128 + i];
  __syncthreads();
  // op head
  for (int o = tid; o < 16 * 64; o += 256) {
    int r = o >> 6, c = o & 63;
    float a = bo1[c];
    for (int k = 0; k < 128; k++) a += es[r * 128 + k] * Wo1[k * 64 + c];
    t1[o] = fmaxf(a, 0.f);
  }
  __syncthreads();
  for (int o = tid; o < 16 * 13; o += 256) {
    int r = o / 13, c = o - r * 13;
    float a = bo2[c];
    for (int k = 0; k < 64; k++) a += t1[r * 64 + k] * Wo2[k * 13 + c];
    out_op[(size_t)(g0 + r) * 13 + c] = a;
  }
  __syncthreads();
  // param head
  for (int o = tid; o < 16 * 64; o += 256) {
    int r = o >> 6, c = o & 63;
    float a = bp1[c];
    for (int k = 0; k < 128; k++) a += es[r * 128 + k] * Wp1[k * 64 + c];
    t1[o] = fmaxf(a, 0.f);
  }
  __syncthreads();
  for (int o = tid; o < 16 * 64; o += 256) {
    int r = o >> 6, c = o & 63;
    float a = bp2[c];
    for (int k = 0; k < 64; k++) a += t1[r * 64 + k] * Wp2[k * 64 + c];
    t2[o] = fmaxf(a, 0.f);
  }
  __syncthreads();
  for (int o = tid; o < 16; o += 256) {
    float a = bp3[0];
    for (int k = 0; k < 64; k++) a += t2[o * 64 + k] * Wp3[k];
    out_p[g0 + o] = a;
  }
  __syncthreads();
  // done head
  for (int o = tid; o < 16 * 64; o += 256) {
    int r = o >> 6, c = o & 63;
    float a = bd1[c];
    for (int k = 0; k < 128; k++) a += es[r * 128 + k] * Wd1[k * 64 + c];
    t1[o] = fmaxf(a, 0.f);
  }
  __syncthreads();
  for (int o = tid; o < 16 * 2; o += 256) {
    int r = o >> 1, c = o & 1;
    float a = bd2[c];
    for (int k = 0; k < 64; k++) a += t1[r * 64 + k] * Wd2[k * 2 + c];
    out_d[(size_t)(g0 + r) * 2 + c] = a;
  }
}

// ---------------- launch ----------------

extern "C" void kernel_launch(void* const* d_in, const int* in_sizes, int n_in,
                              void* d_out, int out_size, void* d_ws, size_t ws_size,
                              hipStream_t stream) {
  const float* x   = (const float*)d_in[0];
  const int*   ei  = (const int*)d_in[1];
  const int*   bat = (const int*)d_in[2];
  const float* W1 = (const float*)d_in[3];  const float* b1  = (const float*)d_in[4];
  const float* g1 = (const float*)d_in[5];  const float* bt1 = (const float*)d_in[6];
  const float* W2 = (const float*)d_in[7];  const float* b2  = (const float*)d_in[8];
  const float* g2 = (const float*)d_in[9];  const float* bt2 = (const float*)d_in[10];
  const float* W3 = (const float*)d_in[11]; const float* b3  = (const float*)d_in[12];
  const float* Wo1 = (const float*)d_in[13]; const float* bo1 = (const float*)d_in[14];
  const float* Wo2 = (const float*)d_in[15]; const float* bo2 = (const float*)d_in[16];
  const float* Wp1 = (const float*)d_in[17]; const float* bp1 = (const float*)d_in[18];
  const float* Wp2 = (const float*)d_in[19]; const float* bp2 = (const float*)d_in[20];
  const float* Wp3 = (const float*)d_in[21]; const float* bp3 = (const float*)d_in[22];
  const float* Wd1 = (const float*)d_in[23]; const float* bd1 = (const float*)d_in[24];
  const float* Wd2 = (const float*)d_in[25]; const float* bd2 = (const float*)d_in[26];

  int N = in_sizes[0] / 20;
  int E = in_sizes[1] / 2;
  int B = out_size / 144;  // 13 + 1 + 2 + 128
  const int* esrc = ei;
  const int* edst = ei + E;

  char* ws = (char*)d_ws;
  size_t off = 0;
  auto alloc = [&](size_t bytes) -> char* {
    char* p = ws + off;
    off = (off + bytes + 255) & ~(size_t)255;
    return p;
  };
  int*   deg_cnt = (int*)alloc((size_t)N * 4);
  float* dinv    = (float*)alloc((size_t)N * 4);
  int*   offs    = (int*)alloc(((size_t)N + 1) * 4);
  int*   cursor  = (int*)alloc((size_t)N * 4);
  int*   bsum    = (int*)alloc(128 * 4);
  int*   cnt_b   = (int*)alloc((size_t)B * 4);
  int*   goffs   = (int*)alloc((size_t)B * 4);
  float* bn      = (float*)alloc(512 * 4);
  int*   csr     = (int*)alloc((size_t)E * 4);
  float* bufA    = (float*)alloc((size_t)N * 128 * 4);
  float* bufB    = (float*)alloc((size_t)N * 128 * 4);

  float* bn_sum1 = bn,       *bn_sq1 = bn + 64;
  float* bn_sum2 = bn + 128, *bn_sq2 = bn + 192;
  float* a1 = bn + 256, *c1 = bn + 320;
  float* a2 = bn + 384, *c2 = bn + 448;

  float* out_op = (float*)d_out;
  float* out_p  = out_op + (size_t)B * 13;
  float* out_d  = out_p + B;
  float* enc    = out_d + (size_t)B * 2;

  hipLaunchKernelGGL(zero_kernel, dim3(512), dim3(256), 0, stream, deg_cnt, cnt_b, bn, N, B);
  hipLaunchKernelGGL(hist_kernel, dim3(2048), dim3(256), 0, stream, edst, bat, deg_cnt, cnt_b, E, N);
  hipLaunchKernelGGL(dinv_kernel, dim3((N + 255) / 256), dim3(256), 0, stream, deg_cnt, dinv, N);
  int nb1 = (N + 1023) / 1024;
  hipLaunchKernelGGL(scan_p1, dim3(nb1), dim3(1024), 0, stream, deg_cnt, offs, bsum, N);
  hipLaunchKernelGGL(scan_p2, dim3(1), dim3(128), 0, stream, bsum, nb1);
  hipLaunchKernelGGL(scan_p3, dim3(nb1), dim3(1024), 0, stream, offs, cursor, bsum, N, E);
  hipLaunchKernelGGL(scan_batch, dim3(1), dim3(1024), 0, stream, cnt_b, goffs, B);
  hipLaunchKernelGGL(csr_fill, dim3(2048), dim3(256), 0, stream, edst, esrc, cursor, csr, E);

  int gblocks = (N + 63) / 64;
  // layer 1
  hipLaunchKernelGGL((gemm_kernel<20, 64, false>), dim3(gblocks), dim3(256), 0, stream,
                     x, W1, nullptr, nullptr, dinv, bufA, N);
  hipLaunchKernelGGL(agg64_kernel, dim3(2048), dim3(256), 0, stream,
                     bufA, offs, csr, dinv, b1, bufB, bn_sum1, bn_sq1, N);
  hipLaunchKernelGGL(bn_final_kernel, dim3(1), dim3(64), 0, stream,
                     bn_sum1, bn_sq1, g1, bt1, a1, c1, (float)N);
  // layer 2
  hipLaunchKernelGGL((gemm_kernel<64, 64, true>), dim3(gblocks), dim3(256), 0, stream,
                     bufB, W2, a1, c1, dinv, bufA, N);
  hipLaunchKernelGGL(agg64_kernel, dim3(2048), dim3(256), 0, stream,
                     bufA, offs, csr, dinv, b2, bufB, bn_sum2, bn_sq2, N);
  hipLaunchKernelGGL(bn_final_kernel, dim3(1), dim3(64), 0, stream,
                     bn_sum2, bn_sq2, g2, bt2, a2, c2, (float)N);
  // layer 3
  hipLaunchKernelGGL((gemm_kernel<64, 128, true>), dim3(gblocks), dim3(256), 0, stream,
                     bufB, W3, a2, c2, dinv, bufA, N);
  hipLaunchKernelGGL(agg128_kernel, dim3(2048), dim3(256), 0, stream,
                     bufA, offs, csr, dinv, b3, bufB, N);
  // pool + heads
  hipLaunchKernelGGL(pool_kernel, dim3(B), dim3(128), 0, stream, bufB, goffs, cnt_b, enc, B);
  hipLaunchKernelGGL(heads_kernel, dim3(B / 16), dim3(256), 0, stream, enc,
                     Wo1, bo1, Wo2, bo2, Wp1, bp1, Wp2, bp2, Wp3, bp3, Wd1, bd1, Wd2, bd2,
                     out_op, out_p, out_d, B);
}

// Round 5
// 613.523 us; speedup vs baseline: 1.4245x; 1.4245x over previous
//
#include <hip/hip_runtime.h>

#define BN_EPS 1e-5f

constexpr int BSH = 9;          // 512 nodes per bucket
constexpr int MAXB = 200;       // max buckets supported (N <= 102400)
constexpr int CAP = 12288;      // temp capacity (pairs) per bucket
constexpr int BINCAP = 32;      // LDS bin capacity per bucket (pairs)
constexpr int FLUSH = 16;       // flush granularity (pairs)

// ---------------- init ----------------

__global__ void initk(int* __restrict__ gcur, float* __restrict__ bn, int NB) {
  int t = blockIdx.x * blockDim.x + threadIdx.x;
  if (t < NB) gcur[t] = t * CAP;
  if (t < 512) bn[t] = 0.f;
}

// goffs from sorted batch: goffs[g] = first node index of graph g; goffs[B] = N
__global__ void bound_kernel(const int* __restrict__ batch, int* __restrict__ goffs, int N, int B) {
  int i = blockIdx.x * blockDim.x + threadIdx.x;
  if (i < N) {
    int b = batch[i];
    int p = (i == 0) ? -1 : batch[i - 1];
    for (int g = p + 1; g <= b; ++g) goffs[g] = i;
    if (i == N - 1) {
      for (int g = b + 1; g <= B; ++g) goffs[g] = N;
    }
  }
}

// ---------------- bucketed CSR build ----------------
// pass A: bin (dst,src) pairs into per-bucket regions of temp, LDS-staged so
// global writes happen in contiguous runs of FLUSH pairs (128B).

__global__ __launch_bounds__(256) void passA(const int* __restrict__ dst, const int* __restrict__ src,
                                             int* __restrict__ gcur, unsigned long long* __restrict__ temp,
                                             int E, int NB) {
  __shared__ unsigned long long bins[MAXB * BINCAP];
  __shared__ int bcnt[MAXB];
  int tid = threadIdx.x;
  for (int b = tid; b < NB; b += 256) bcnt[b] = 0;
  __syncthreads();
  int chunk = (E + gridDim.x - 1) / gridDim.x;
  int e0 = blockIdx.x * chunk;
  int e1 = min(e0 + chunk, E);
  for (int base = e0; base < e1; base += 1024) {
#pragma unroll
    for (int j = 0; j < 4; ++j) {
      int e = base + tid * 4 + j;
      if (e < e1) {
        int d = dst[e];
        int s = src[e];
        int b = d >> BSH;
        unsigned long long pk = ((unsigned long long)(unsigned)s << 32) | (unsigned)d;
        int slot = atomicAdd(&bcnt[b], 1);
        if (slot < BINCAP) {
          bins[b * BINCAP + slot] = pk;
        } else {  // rare spill: direct global (correctness fallback)
          int p = atomicAdd(&gcur[b], 1);
          temp[p] = pk;
        }
      }
    }
    __syncthreads();
    if (tid < NB) {
      int c = min(bcnt[tid], BINCAP);
      while (c >= FLUSH) {
        int p = atomicAdd(&gcur[tid], FLUSH);
        for (int j = 0; j < FLUSH; ++j) temp[p + j] = bins[tid * BINCAP + j];
        c -= FLUSH;
        for (int j = 0; j < c; ++j) bins[tid * BINCAP + j] = bins[tid * BINCAP + FLUSH + j];
      }
      bcnt[tid] = c;
    }
    __syncthreads();
  }
  if (tid < NB) {
    int c = min(bcnt[tid], BINCAP);
    if (c > 0) {
      int p = atomicAdd(&gcur[tid], c);
      for (int j = 0; j < c; ++j) temp[p + j] = bins[tid * BINCAP + j];
    }
  }
}

// pass B1: per-bucket LDS histogram -> deg + dinv (coalesced writes, no global atomics)
__global__ __launch_bounds__(512) void passB1(const unsigned long long* __restrict__ temp,
                                              const int* __restrict__ gcur,
                                              int* __restrict__ deg, float* __restrict__ dinv, int N) {
  __shared__ int h[512];
  int b = blockIdx.x, t = threadIdx.x;
  h[t] = 0;
  __syncthreads();
  int cnt = min(gcur[b] - b * CAP, CAP);
  const unsigned long long* tp = temp + (size_t)b * CAP;
  for (int i = t; i < cnt; i += 512) {
    int d = (int)(tp[i] & 0xffffffffu);
    atomicAdd(&h[d & 511], 1);
  }
  __syncthreads();
  int node = (b << BSH) + t;
  if (node < N) {
    deg[node] = h[t];
    dinv[node] = rsqrtf((float)h[t] + 1.f);
  }
}

// pass B2: fine scatter into csr; all writes land in this bucket's 32KB csr window (L2-local)
__global__ __launch_bounds__(512) void passB2(const unsigned long long* __restrict__ temp,
                                              const int* __restrict__ gcur,
                                              const int* __restrict__ offs,
                                              int* __restrict__ csr, int N) {
  __shared__ int lofs[512];
  __shared__ int lcnt[512];
  int b = blockIdx.x, t = threadIdx.x;
  int node = (b << BSH) + t;
  lofs[t] = offs[min(node, N)];
  lcnt[t] = 0;
  __syncthreads();
  int cnt = min(gcur[b] - b * CAP, CAP);
  const unsigned long long* tp = temp + (size_t)b * CAP;
  for (int i = t; i < cnt; i += 512) {
    unsigned long long pk = tp[i];
    int d = (int)(pk & 0xffffffffu) & 511;
    int s = (int)(pk >> 32);
    int pos = lofs[d] + atomicAdd(&lcnt[d], 1);
    csr[pos] = s;
  }
}

// ---------------- 3-phase exclusive scan for CSR offsets ----------------

__global__ __launch_bounds__(1024) void scan_p1(const int* __restrict__ cnt,
                                                int* __restrict__ offs,
                                                int* __restrict__ bsum, int n) {
  __shared__ int sh[1024];
  int t = threadIdx.x;
  int i = blockIdx.x * 1024 + t;
  int v = (i < n) ? cnt[i] : 0;
  sh[t] = v;
  __syncthreads();
  for (int d = 1; d < 1024; d <<= 1) {
    int x = (t >= d) ? sh[t - d] : 0;
    __syncthreads();
    sh[t] += x;
    __syncthreads();
  }
  if (i < n) offs[i] = sh[t] - v;
  if (t == 1023) bsum[blockIdx.x] = sh[t];
}

__global__ void scan_p2(int* __restrict__ bsum, int nb) {
  __shared__ int sh[128];
  int t = threadIdx.x;
  int v = (t < nb) ? bsum[t] : 0;
  sh[t] = v;
  __syncthreads();
  for (int d = 1; d < 128; d <<= 1) {
    int x = (t >= d) ? sh[t - d] : 0;
    __syncthreads();
    sh[t] += x;
    __syncthreads();
  }
  if (t < nb) bsum[t] = sh[t] - v;
}

__global__ __launch_bounds__(1024) void scan_p3(int* __restrict__ offs,
                                                const int* __restrict__ bsum, int n, int E) {
  int i = blockIdx.x * 1024 + threadIdx.x;
  if (i < n) offs[i] += bsum[blockIdx.x];
  if (i == 0) offs[n] = E;
}

// ---------------- pre-layer transforms ----------------

// u1[i][f] = x[i][f] * dinv[i], padded 20 -> 32
__global__ void pre1_kernel(const float* __restrict__ x, const float* __restrict__ dinv,
                            float* __restrict__ u1, int N) {
  int stride = gridDim.x * blockDim.x;
  for (int i = blockIdx.x * blockDim.x + threadIdx.x; i < N * 32; i += stride) {
    int row = i >> 5, f = i & 31;
    u1[i] = (f < 20) ? x[row * 20 + f] * dinv[row] : 0.f;
  }
}

// u = relu(z*ta+tc) * dinv   (fused BN-affine + ReLU + row scaling)
__global__ void u_kernel(const float* __restrict__ z, const float* __restrict__ ta,
                         const float* __restrict__ tc, const float* __restrict__ dinv,
                         float* __restrict__ u, int N) {
  int stride = gridDim.x * blockDim.x;
  for (int i = blockIdx.x * blockDim.x + threadIdx.x; i < N * 16; i += stride) {
    int row = i >> 4, f = (i & 15) * 4;
    float4 v = ((const float4*)z)[i];
    float dv = dinv[row];
    float4 o;
    o.x = fmaxf(v.x * ta[f] + tc[f], 0.f) * dv;
    o.y = fmaxf(v.y * ta[f + 1] + tc[f + 1], 0.f) * dv;
    o.z = fmaxf(v.z * ta[f + 2] + tc[f + 2], 0.f) * dv;
    o.w = fmaxf(v.w * ta[f + 3] + tc[f + 3], 0.f) * dv;
    ((float4*)u)[i] = o;
  }
}

// ---------------- aggregation (pure gather-sum; pre-GEMM space) ----------------

// 32-dim (padded 20): 2 neighbors per wave iteration (lane = nbr*32 + feat)
__global__ __launch_bounds__(256) void agg32_kernel(const float* __restrict__ u,
                                                    const int* __restrict__ offs,
                                                    const int* __restrict__ csr,
                                                    float* __restrict__ out, int n) {
  int lane = threadIdx.x & 63;
  int wid = threadIdx.x >> 6;
  int half = lane >> 5, f = lane & 31;
  int gw = blockIdx.x * 4 + wid, nw = gridDim.x * 4;
  for (int i = gw; i < n; i += nw) {
    float acc = half ? 0.f : u[(size_t)i * 32 + f];
    int st = offs[i], en = offs[i + 1];
    for (int base = st; base < en; base += 64) {
      int idx = base + lane;
      int v = (idx < en) ? csr[idx] : 0;
      int cnt = min(64, en - base);
      int j = 0;
      for (; j + 3 < cnt; j += 4) {
        int s0 = __shfl(v, j + half);
        int s1 = __shfl(v, j + 2 + half);
        acc += u[(size_t)s0 * 32 + f] + u[(size_t)s1 * 32 + f];
      }
      for (; j < cnt; ++j) {
        int s = __shfl(v, j);
        if (!half) acc += u[(size_t)s * 32 + f];
      }
    }
    acc += __shfl_xor(acc, 32);
    if (!half) out[(size_t)i * 32 + f] = acc;
  }
}

// 64-dim; SCALE multiplies result by dinv[i] (layer-3 pre-pool form)
template <bool SCALE>
__global__ __launch_bounds__(256) void agg64_kernel(const float* __restrict__ u,
                                                    const int* __restrict__ offs,
                                                    const int* __restrict__ csr,
                                                    const float* __restrict__ dinv,
                                                    float* __restrict__ out, int n) {
  int lane = threadIdx.x & 63;
  int wid = threadIdx.x >> 6;
  int gw = blockIdx.x * 4 + wid, nw = gridDim.x * 4;
  for (int i = gw; i < n; i += nw) {
    float acc = u[(size_t)i * 64 + lane];
    int st = offs[i], en = offs[i + 1];
    for (int base = st; base < en; base += 64) {
      int idx = base + lane;
      int v = (idx < en) ? csr[idx] : 0;
      int cnt = min(64, en - base);
      int j = 0;
      for (; j + 3 < cnt; j += 4) {
        int s0 = __shfl(v, j), s1 = __shfl(v, j + 1);
        int s2 = __shfl(v, j + 2), s3 = __shfl(v, j + 3);
        acc += u[(size_t)s0 * 64 + lane] + u[(size_t)s1 * 64 + lane] +
               u[(size_t)s2 * 64 + lane] + u[(size_t)s3 * 64 + lane];
      }
      for (; j < cnt; ++j) {
        int s = __shfl(v, j);
        acc += u[(size_t)s * 64 + lane];
      }
    }
    if (SCALE) acc *= dinv[i];
    out[(size_t)i * 64 + lane] = acc;
  }
}

// ---------------- GEMM on aggregated input: z = dinv*(a@W) + bias, + BN stats ----------------

template <int K, int AS>  // K = inner dim, AS = global row stride of A
__global__ __launch_bounds__(256) void gemm_agg(const float* __restrict__ A, const float* __restrict__ W,
                                                const float* __restrict__ bias, const float* __restrict__ dinv,
                                                float* __restrict__ z, float* __restrict__ bn_sum,
                                                float* __restrict__ bn_sq, int n) {
  __shared__ float Ws[K * 64];
  __shared__ float As[64 * (K + 1)];
  __shared__ float bnS[64], bnQ[64];
  int tid = threadIdx.x;
  if (tid < 64) { bnS[tid] = 0.f; bnQ[tid] = 0.f; }
  int row0 = blockIdx.x * 64;
  for (int i = tid; i < K * 64; i += 256) Ws[i] = W[i];
  for (int i = tid; i < 64 * K; i += 256) {
    int r = i / K, k = i - r * K;
    int gr = row0 + r;
    As[r * (K + 1) + k] = (gr < n) ? A[(size_t)gr * AS + k] : 0.f;
  }
  __syncthreads();
  int rl = tid >> 2, fs = tid & 3;
  float acc[16];
#pragma unroll
  for (int j = 0; j < 16; ++j) acc[j] = 0.f;
  const float* ab = &As[rl * (K + 1)];
  const float* wb = &Ws[fs * 16];
  for (int k = 0; k < K; ++k) {
    float a = ab[k];
#pragma unroll
    for (int j = 0; j < 16; ++j) acc[j] += a * wb[k * 64 + j];
  }
  int gr = row0 + rl;
  if (gr < n) {
    float dv = dinv[gr];
#pragma unroll
    for (int j = 0; j < 16; ++j) {
      int f = fs * 16 + j;
      float o = acc[j] * dv + bias[f];
      acc[j] = o;
      atomicAdd(&bnS[f], o);
      atomicAdd(&bnQ[f], o * o);
    }
    float4* zp = (float4*)&z[(size_t)gr * 64 + fs * 16];
#pragma unroll
    for (int j = 0; j < 16; j += 4)
      zp[j >> 2] = make_float4(acc[j], acc[j + 1], acc[j + 2], acc[j + 3]);
  }
  __syncthreads();
  if (tid < 64) {
    atomicAdd(&bn_sum[tid], bnS[tid]);
    atomicAdd(&bn_sq[tid], bnQ[tid]);
  }
}

// ---------------- BN finalize ----------------

__global__ void bn_final_kernel(const float* __restrict__ sum, const float* __restrict__ sq,
                                const float* __restrict__ g, const float* __restrict__ bt,
                                float* __restrict__ a, float* __restrict__ c, float n) {
  int f = threadIdx.x;
  float mu = sum[f] / n;
  float var = fmaxf(sq[f] / n - mu * mu, 0.f);
  float rstd = rsqrtf(var + BN_EPS);
  float av = g[f] * rstd;
  a[f] = av;
  c[f] = bt[f] - mu * av;
}

// ---------------- pool: ep[b] = mean over graph rows of v3 (64-dim) ----------------

__global__ __launch_bounds__(64) void pool_kernel(const float* __restrict__ v3,
                                                  const int* __restrict__ goffs,
                                                  float* __restrict__ ep, int B) {
  int b = blockIdx.x, t = threadIdx.x;
  int st = goffs[b], en = goffs[b + 1];
  float s = 0.f;
  int r = st;
  for (; r + 1 < en; r += 2) s += v3[(size_t)r * 64 + t] + v3[(size_t)(r + 1) * 64 + t];
  if (r < en) s += v3[(size_t)r * 64 + t];
  int c = en - st;
  ep[(size_t)b * 64 + t] = s / (float)max(c, 1);
}

// ---------------- heads: enc = ep@W3 + b3, then 3 MLP heads (16 graphs/block) ----------------

__global__ __launch_bounds__(256) void heads_kernel(
    const float* __restrict__ ep, const int* __restrict__ goffs,
    const float* __restrict__ W3, const float* __restrict__ b3,
    const float* __restrict__ Wo1, const float* __restrict__ bo1,
    const float* __restrict__ Wo2, const float* __restrict__ bo2,
    const float* __restrict__ Wp1, const float* __restrict__ bp1,
    const float* __restrict__ Wp2, const float* __restrict__ bp2,
    const float* __restrict__ Wp3, const float* __restrict__ bp3,
    const float* __restrict__ Wd1, const float* __restrict__ bd1,
    const float* __restrict__ Wd2, const float* __restrict__ bd2,
    float* __restrict__ out_op, float* __restrict__ out_p, float* __restrict__ out_d,
    float* __restrict__ enc_out, int B) {
  __shared__ float epl[16 * 64];
  __shared__ float es[16 * 128];
  __shared__ float t1[16 * 64];
  __shared__ float t2[16 * 64];
  int tid = threadIdx.x;
  int g0 = blockIdx.x * 16;
  for (int i = tid; i < 16 * 64; i += 256) epl[i] = ep[(size_t)g0 * 64 + i];
  __syncthreads();
  // enc = ep @ W3 + b3  (zero for empty graphs, matching ref 0/max(cnt,1))
  for (int o = tid; o < 16 * 128; o += 256) {
    int r = o >> 7, c = o & 127;
    float a = b3[c];
    for (int k = 0; k < 64; ++k) a += epl[r * 64 + k] * W3[k * 128 + c];
    if (goffs[g0 + r + 1] - goffs[g0 + r] == 0) a = 0.f;
    es[o] = a;
    enc_out[(size_t)(g0 + r) * 128 + c] = a;
  }
  __syncthreads();
  // op head
  for (int o = tid; o < 16 * 64; o += 256) {
    int r = o >> 6, c = o & 63;
    float a = bo1[c];
    for (int k = 0; k < 128; k++) a += es[r * 128 + k] * Wo1[k * 64 + c];
    t1[o] = fmaxf(a, 0.f);
  }
  __syncthreads();
  for (int o = tid; o < 16 * 13; o += 256) {
    int r = o / 13, c = o - r * 13;
    float a = bo2[c];
    for (int k = 0; k < 64; k++) a += t1[r * 64 + k] * Wo2[k * 13 + c];
    out_op[(size_t)(g0 + r) * 13 + c] = a;
  }
  __syncthreads();
  // param head
  for (int o = tid; o < 16 * 64; o += 256) {
    int r = o >> 6, c = o & 63;
    float a = bp1[c];
    for (int k = 0; k < 128; k++) a += es[r * 128 + k] * Wp1[k * 64 + c];
    t1[o] = fmaxf(a, 0.f);
  }
  __syncthreads();
  for (int o = tid; o < 16 * 64; o += 256) {
    int r = o >> 6, c = o & 63;
    float a = bp2[c];
    for (int k = 0; k < 64; k++) a += t1[r * 64 + k] * Wp2[k * 64 + c];
    t2[o] = fmaxf(a, 0.f);
  }
  __syncthreads();
  for (int o = tid; o < 16; o += 256) {
    float a = bp3[0];
    for (int k = 0; k < 64; k++) a += t2[o * 64 + k] * Wp3[k];
    out_p[g0 + o] = a;
  }
  __syncthreads();
  // done head
  for (int o = tid; o < 16 * 64; o += 256) {
    int r = o >> 6, c = o & 63;
    float a = bd1[c];
    for (int k = 0; k < 128; k++) a += es[r * 128 + k] * Wd1[k * 64 + c];
    t1[o] = fmaxf(a, 0.f);
  }
  __syncthreads();
  for (int o = tid; o < 16 * 2; o += 256) {
    int r = o >> 1, c = o & 1;
    float a = bd2[c];
    for (int k = 0; k < 64; k++) a += t1[r * 64 + k] * Wd2[k * 2 + c];
    out_d[(size_t)(g0 + r) * 2 + c] = a;
  }
}

// ---------------- launch ----------------

extern "C" void kernel_launch(void* const* d_in, const int* in_sizes, int n_in,
                              void* d_out, int out_size, void* d_ws, size_t ws_size,
                              hipStream_t stream) {
  const float* x   = (const float*)d_in[0];
  const int*   ei  = (const int*)d_in[1];
  const int*   bat = (const int*)d_in[2];
  const float* W1 = (const float*)d_in[3];  const float* b1  = (const float*)d_in[4];
  const float* g1 = (const float*)d_in[5];  const float* bt1 = (const float*)d_in[6];
  const float* W2 = (const float*)d_in[7];  const float* b2  = (const float*)d_in[8];
  const float* g2 = (const float*)d_in[9];  const float* bt2 = (const float*)d_in[10];
  const float* W3 = (const float*)d_in[11]; const float* b3  = (const float*)d_in[12];
  const float* Wo1 = (const float*)d_in[13]; const float* bo1 = (const float*)d_in[14];
  const float* Wo2 = (const float*)d_in[15]; const float* bo2 = (const float*)d_in[16];
  const float* Wp1 = (const float*)d_in[17]; const float* bp1 = (const float*)d_in[18];
  const float* Wp2 = (const float*)d_in[19]; const float* bp2 = (const float*)d_in[20];
  const float* Wp3 = (const float*)d_in[21]; const float* bp3 = (const float*)d_in[22];
  const float* Wd1 = (const float*)d_in[23]; const float* bd1 = (const float*)d_in[24];
  const float* Wd2 = (const float*)d_in[25]; const float* bd2 = (const float*)d_in[26];

  int N = in_sizes[0] / 20;
  int E = in_sizes[1] / 2;
  int B = out_size / 144;  // 13 + 1 + 2 + 128
  const int* esrc = ei;
  const int* edst = ei + E;
  int NB = (N + (1 << BSH) - 1) >> BSH;  // 196 for N=100000 (<= MAXB)

  char* ws = (char*)d_ws;
  size_t off = 0;
  auto alloc = [&](size_t bytes) -> char* {
    char* p = ws + off;
    off = (off + bytes + 255) & ~(size_t)255;
    return p;
  };
  int*   gcur  = (int*)alloc((size_t)NB * 4);
  int*   deg   = (int*)alloc((size_t)N * 4);
  float* dinv  = (float*)alloc((size_t)N * 4);
  int*   offs  = (int*)alloc(((size_t)N + 1) * 4);
  int*   bsum  = (int*)alloc(128 * 4);
  int*   goffs = (int*)alloc(((size_t)B + 1) * 4);
  float* bn    = (float*)alloc(512 * 4);
  unsigned long long* temp = (unsigned long long*)alloc((size_t)NB * CAP * 8);
  int*   csr   = (int*)alloc((size_t)E * 4);
  float* bufA  = (float*)alloc((size_t)N * 64 * 4);
  float* bufB  = (float*)alloc((size_t)N * 64 * 4);
  float* ep    = (float*)alloc((size_t)B * 64 * 4);

  float* bn_sum1 = bn,       *bn_sq1 = bn + 64;
  float* bn_sum2 = bn + 128, *bn_sq2 = bn + 192;
  float* ta1 = bn + 256, *tc1 = bn + 320;
  float* ta2 = bn + 384, *tc2 = bn + 448;

  float* out_op = (float*)d_out;
  float* out_p  = out_op + (size_t)B * 13;
  float* out_d  = out_p + B;
  float* enc    = out_d + (size_t)B * 2;

  hipLaunchKernelGGL(initk, dim3(2), dim3(256), 0, stream, gcur, bn, NB);
  hipLaunchKernelGGL(bound_kernel, dim3((N + 255) / 256), dim3(256), 0, stream, bat, goffs, N, B);
  hipLaunchKernelGGL(passA, dim3(256), dim3(256), 0, stream, edst, esrc, gcur, temp, E, NB);
  hipLaunchKernelGGL(passB1, dim3(NB), dim3(512), 0, stream, temp, gcur, deg, dinv, N);
  int nb1 = (N + 1023) / 1024;
  hipLaunchKernelGGL(scan_p1, dim3(nb1), dim3(1024), 0, stream, deg, offs, bsum, N);
  hipLaunchKernelGGL(scan_p2, dim3(1), dim3(128), 0, stream, bsum, nb1);
  hipLaunchKernelGGL(scan_p3, dim3(nb1), dim3(1024), 0, stream, offs, bsum, N, E);
  hipLaunchKernelGGL(passB2, dim3(NB), dim3(512), 0, stream, temp, gcur, offs, csr, N);

  int gblocks = (N + 63) / 64;
  // layer 1: u1 = pad32(x)*dinv -> agg -> gemm(20->64) + bn1
  hipLaunchKernelGGL(pre1_kernel, dim3(2048), dim3(256), 0, stream, x, dinv, bufA, N);
  hipLaunchKernelGGL(agg32_kernel, dim3(2048), dim3(256), 0, stream, bufA, offs, csr, bufB, N);
  hipLaunchKernelGGL((gemm_agg<20, 32>), dim3(gblocks), dim3(256), 0, stream,
                     bufB, W1, b1, dinv, bufA, bn_sum1, bn_sq1, N);
  hipLaunchKernelGGL(bn_final_kernel, dim3(1), dim3(64), 0, stream,
                     bn_sum1, bn_sq1, g1, bt1, ta1, tc1, (float)N);
  // layer 2
  hipLaunchKernelGGL(u_kernel, dim3(2048), dim3(256), 0, stream, bufA, ta1, tc1, dinv, bufB, N);
  hipLaunchKernelGGL((agg64_kernel<false>), dim3(2048), dim3(256), 0, stream,
                     bufB, offs, csr, dinv, bufA, N);
  hipLaunchKernelGGL((gemm_agg<64, 64>), dim3(gblocks), dim3(256), 0, stream,
                     bufA, W2, b2, dinv, bufB, bn_sum2, bn_sq2, N);
  hipLaunchKernelGGL(bn_final_kernel, dim3(1), dim3(64), 0, stream,
                     bn_sum2, bn_sq2, g2, bt2, ta2, tc2, (float)N);
  // layer 3 (pre-GEMM space): u3 -> agg (scaled by dinv) -> pool -> enc GEMM in heads
  hipLaunchKernelGGL(u_kernel, dim3(2048), dim3(256), 0, stream, bufB, ta2, tc2, dinv, bufA, N);
  hipLaunchKernelGGL((agg64_kernel<true>), dim3(2048), dim3(256), 0, stream,
                     bufA, offs, csr, dinv, bufB, N);
  hipLaunchKernelGGL(pool_kernel, dim3(B), dim3(64), 0, stream, bufB, goffs, ep, B);
  hipLaunchKernelGGL(heads_kernel, dim3(B / 16), dim3(256), 0, stream, ep, goffs, W3, b3,
                     Wo1, bo1, Wo2, bo2, Wp1, bp1, Wp2, bp2, Wp3, bp3, Wd1, bd1, Wd2, bd2,
                     out_op, out_p, out_d, enc, B);
}